// Round 1
// baseline (474.739 us; speedup 1.0000x reference)
//
#include <hip/hip_runtime.h>
#include <cstdint>
#include <math.h>

#define NB 64
#define NP 8732
#define NC 81
#define NG 16
#define THRESH 0.5f

// ---------------------------------------------------------------------------
// Kernel 1: per-image matching + localization L1 partial sums
// One block (256 threads) per image.
// ---------------------------------------------------------------------------
__global__ __launch_bounds__(256) void match_kernel(
    const float* __restrict__ gt_boxes,    // [B,G,4] corner form
    const int* __restrict__ gt_labels,     // [B,G]
    const float* __restrict__ priors,      // [P,4] center form
    const float* __restrict__ pred_boxes,  // [B,P,4]
    int* __restrict__ conf_out,            // [B,P]
    int* __restrict__ n_pos_out,           // [B]
    double* __restrict__ acc,              // [0]=l1_sum, [1]=pos_loss, [2]=neg_loss
    int* __restrict__ total_pos)
{
    __shared__ float s_ov[NP];
    __shared__ unsigned char s_idx[NP];
    __shared__ float s_gt[NG][4];
    __shared__ float s_ga[NG];
    __shared__ int   s_lab[NG];
    __shared__ float r_val[256];
    __shared__ int   r_idx[256];
    __shared__ int   s_bp[NG];

    const int b = blockIdx.x;
    const int tid = threadIdx.x;

    if (tid < NG * 4) ((float*)s_gt)[tid] = gt_boxes[b * NG * 4 + tid];
    if (tid >= 64 && tid < 64 + NG) s_lab[tid - 64] = gt_labels[b * NG + (tid - 64)];
    __syncthreads();
    if (tid < NG)
        s_ga[tid] = (s_gt[tid][2] - s_gt[tid][0]) * (s_gt[tid][3] - s_gt[tid][1]);
    __syncthreads();

    // Per-thread running best prior per gt (for argmax over P, first-occurrence).
    float bp_val[NG];
    int   bp_pidx[NG];
#pragma unroll
    for (int g = 0; g < NG; ++g) { bp_val[g] = -1.0f; bp_pidx[g] = 0; }

    for (int p = tid; p < NP; p += 256) {
        const float4 pr = ((const float4*)priors)[p];
        const float px1 = pr.x - pr.z / 2.0f;
        const float py1 = pr.y - pr.w / 2.0f;
        const float px2 = pr.x + pr.z / 2.0f;
        const float py2 = pr.y + pr.w / 2.0f;
        const float ap = (px2 - px1) * (py2 - py1);
        float bt_ov = -1.0f;
        int   bt_idx = 0;
#pragma unroll
        for (int g = 0; g < NG; ++g) {
            const float ltx = fmaxf(s_gt[g][0], px1);
            const float lty = fmaxf(s_gt[g][1], py1);
            const float rbx = fminf(s_gt[g][2], px2);
            const float rby = fminf(s_gt[g][3], py2);
            const float wx = fmaxf(rbx - ltx, 0.0f);
            const float wy = fmaxf(rby - lty, 0.0f);
            const float inter = wx * wy;
            const float iou = inter / (s_ga[g] + ap - inter);
            if (iou > bt_ov) { bt_ov = iou; bt_idx = g; }       // first max over g
            if (iou > bp_val[g]) { bp_val[g] = iou; bp_pidx[g] = p; } // first max over p (p ascending)
        }
        s_ov[p] = bt_ov;
        s_idx[p] = (unsigned char)bt_idx;
    }
    __syncthreads();

    // Block-reduce per-gt best prior (argmax over P; tie -> smaller index).
#pragma unroll
    for (int g = 0; g < NG; ++g) {
        r_val[tid] = bp_val[g];
        r_idx[tid] = bp_pidx[g];
        __syncthreads();
        for (int s = 128; s > 0; s >>= 1) {
            if (tid < s) {
                const float v2 = r_val[tid + s];
                const int   i2 = r_idx[tid + s];
                if (v2 > r_val[tid] || (v2 == r_val[tid] && i2 < r_idx[tid])) {
                    r_val[tid] = v2; r_idx[tid] = i2;
                }
            }
            __syncthreads();
        }
        if (tid == 0) s_bp[g] = r_idx[0];
        __syncthreads();
    }

    // Sequential scatter override: g ascending, later g wins on duplicates.
    if (tid == 0) {
        for (int g = 0; g < NG; ++g) {
            const int p = s_bp[g];
            s_ov[p] = 2.0f;
            s_idx[p] = (unsigned char)g;
        }
    }
    __syncthreads();

    // Confidence targets, positives count, encode + L1 on positives.
    int my_npos = 0;
    float my_l1 = 0.0f;
    for (int p = tid; p < NP; p += 256) {
        const int g = s_idx[p];
        const float ov = s_ov[p];
        const int cf = (ov < THRESH) ? 0 : s_lab[g];
        conf_out[(size_t)b * NP + p] = cf;
        if (cf != 0) {
            ++my_npos;
            const float4 pr = ((const float4*)priors)[p];
            const float x1 = s_gt[g][0], y1 = s_gt[g][1];
            const float x2 = s_gt[g][2], y2 = s_gt[g][3];
            const float mcx = (x1 + x2) / 2.0f;
            const float mcy = (y1 + y2) / 2.0f;
            const float mw = x2 - x1, mh = y2 - y1;
            const float gx = (mcx - pr.x) / (0.1f * pr.z);
            const float gy = (mcy - pr.y) / (0.1f * pr.w);
            const float gw = logf(mw / pr.z) / 0.2f;
            const float gh = logf(mh / pr.w) / 0.2f;
            const float4 pb = ((const float4*)pred_boxes)[(size_t)b * NP + p];
            my_l1 += fabsf(pb.x - gx) + fabsf(pb.y - gy) +
                     fabsf(pb.z - gw) + fabsf(pb.w - gh);
        }
    }

    r_val[tid] = my_l1;
    r_idx[tid] = my_npos;
    __syncthreads();
    for (int s = 128; s > 0; s >>= 1) {
        if (tid < s) { r_val[tid] += r_val[tid + s]; r_idx[tid] += r_idx[tid + s]; }
        __syncthreads();
    }
    if (tid == 0) {
        n_pos_out[b] = r_idx[0];
        atomicAdd(total_pos, r_idx[0]);
        atomicAdd(&acc[0], (double)r_val[0]);
    }
}

// ---------------------------------------------------------------------------
// Kernel 2: per-prior cross entropy (one wave per prior). Reads the 181 MB
// scores tensor once, coalesced 256B per wave per load.
// ---------------------------------------------------------------------------
__global__ __launch_bounds__(256) void ce_kernel(
    const float* __restrict__ scores,   // [B*P, C]
    const int* __restrict__ conf,       // [B*P]
    float* __restrict__ ce_neg,         // [B*P]
    double* __restrict__ acc)           // [1]=pos_loss
{
    const int lane = threadIdx.x & 63;
    const int wid = threadIdx.x >> 6;
    const int gwave = blockIdx.x * 4 + wid;
    const int nwaves = gridDim.x * 4;
    const int N = NB * NP;
    float my_pos = 0.0f;

    for (int i = gwave; i < N; i += nwaves) {
        const float* base = scores + (size_t)i * NC;
        const float v0 = base[lane];
        const float v1 = (lane < NC - 64) ? base[64 + lane] : -INFINITY;

        // max over 81 classes (butterfly -> all lanes)
        float m = fmaxf(v0, v1);
#pragma unroll
        for (int off = 32; off > 0; off >>= 1)
            m = fmaxf(m, __shfl_xor(m, off, 64));

        float s = expf(v0 - m) + ((lane < NC - 64) ? expf(v1 - m) : 0.0f);
#pragma unroll
        for (int off = 32; off > 0; off >>= 1)
            s += __shfl_down(s, off, 64);

        const int c = conf[i];
        float sc = (lane == c) ? v0
                 : ((64 + lane == c && lane < NC - 64) ? v1 : -INFINITY);
#pragma unroll
        for (int off = 32; off > 0; off >>= 1)
            sc = fmaxf(sc, __shfl_down(sc, off, 64));

        if (lane == 0) {
            const float ce = m + logf(s) - sc;
            if (c != 0) { my_pos += ce; ce_neg[i] = 0.0f; }
            else        { ce_neg[i] = ce; }
        }
    }

    __shared__ float red[256];
    red[threadIdx.x] = my_pos;
    __syncthreads();
    for (int s = 128; s > 0; s >>= 1) {
        if (threadIdx.x < s) red[threadIdx.x] += red[threadIdx.x + s];
        __syncthreads();
    }
    if (threadIdx.x == 0 && red[0] != 0.0f) atomicAdd(&acc[1], (double)red[0]);
}

// ---------------------------------------------------------------------------
// Kernel 3: hard-negative mining — exact top-k sum via radix select on float
// bits (all values >= 0 so uint order == float order). One block per image.
// sum(top-k of desc-sorted) == sum_{v>T} v + (k - count(v>T)) * T, tie-exact.
// ---------------------------------------------------------------------------
__global__ __launch_bounds__(256) void mine_kernel(
    const float* __restrict__ ce_neg,   // [B,P]
    const int* __restrict__ n_pos,      // [B]
    double* __restrict__ acc)           // [2]=neg_loss
{
    __shared__ int hist[256];
    __shared__ int s_digit, s_rem;
    __shared__ float red[256];

    const int b = blockIdx.x;
    const int tid = threadIdx.x;
    const float* x = ce_neg + (size_t)b * NP;

    int k = 3 * n_pos[b];
    if (k > NP) k = NP;
    if (k <= 0) return;  // uniform across block

    unsigned int prefix = 0;
    int rem = k;
    for (int shift = 24; shift >= 0; shift -= 8) {
        hist[tid] = 0;
        __syncthreads();
        for (int p = tid; p < NP; p += 256) {
            const unsigned int v = __float_as_uint(x[p]);
            const bool match =
                (shift == 24) || ((v >> (shift + 8)) == (prefix >> (shift + 8)));
            if (match) atomicAdd(&hist[(v >> shift) & 255], 1);
        }
        __syncthreads();
        if (tid == 0) {
            int csum = 0, d = 255;
            for (; d >= 0; --d) { csum += hist[d]; if (csum >= rem) break; }
            if (d < 0) d = 0;  // defensive; invariant guarantees not hit
            s_digit = d;
            s_rem = rem - (csum - hist[d]);
        }
        __syncthreads();
        prefix |= ((unsigned int)s_digit) << shift;
        rem = s_rem;
        __syncthreads();
    }

    // Sum strictly-greater values; add rem copies of the threshold value T.
    float local = 0.0f;
    for (int p = tid; p < NP; p += 256) {
        const unsigned int v = __float_as_uint(x[p]);
        if (v > prefix) local += x[p];
    }
    red[tid] = local;
    __syncthreads();
    for (int s = 128; s > 0; s >>= 1) {
        if (tid < s) red[tid] += red[tid + s];
        __syncthreads();
    }
    if (tid == 0) {
        const double total =
            (double)red[0] + (double)rem * (double)__uint_as_float(prefix);
        atomicAdd(&acc[2], total);
    }
}

// ---------------------------------------------------------------------------
// Kernel 4: finalize the two scalar losses.
// ---------------------------------------------------------------------------
__global__ void finalize_kernel(const double* __restrict__ acc,
                                const int* __restrict__ total_pos,
                                float* __restrict__ out)
{
    const double tp = (double)(*total_pos);
    out[0] = (float)((acc[2] + acc[1]) / tp);       // confidence loss
    out[1] = (float)(acc[0] / (tp * 4.0));          // ALPHA * location loss
}

// ---------------------------------------------------------------------------
extern "C" void kernel_launch(void* const* d_in, const int* in_sizes, int n_in,
                              void* d_out, int out_size, void* d_ws, size_t ws_size,
                              hipStream_t stream)
{
    const float* pred_boxes = (const float*)d_in[0];  // [B,P,4]
    const float* scores     = (const float*)d_in[1];  // [B,P,C]
    const float* gt_boxes   = (const float*)d_in[2];  // [B,G,4]
    const int*   gt_labels  = (const int*)d_in[3];    // [B,G]
    const float* priors     = (const float*)d_in[4];  // [P,4]
    float* out = (float*)d_out;

    char* ws = (char*)d_ws;
    double* acc      = (double*)ws;            // 3 doubles: l1, pos_loss, neg_loss
    int*    totpos   = (int*)(ws + 32);
    int*    n_pos    = (int*)(ws + 64);        // [B]
    int*    conf     = (int*)(ws + 512);                              // [B*P] ints
    float*  ce_neg   = (float*)(ws + 512 + (size_t)NB * NP * sizeof(int)); // [B*P]

    hipMemsetAsync(ws, 0, 512, stream);
    match_kernel<<<NB, 256, 0, stream>>>(gt_boxes, gt_labels, priors, pred_boxes,
                                         conf, n_pos, acc, totpos);
    ce_kernel<<<2048, 256, 0, stream>>>(scores, conf, ce_neg, acc);
    mine_kernel<<<NB, 256, 0, stream>>>(ce_neg, n_pos, acc);
    finalize_kernel<<<1, 1, 0, stream>>>(acc, totpos, out);
}